// Round 8
// baseline (347.708 us; speedup 1.0000x reference)
//
#include <hip/hip_runtime.h>
#include <math.h>

#define B_TOTAL 16384
#define T_STEPS 20
#define NGRP    1024            // B_TOTAL/16 batch groups per sensor

#define LOG2E    1.44269504088896f
#define TWOLOG2E 2.88539008177793f

typedef __attribute__((ext_vector_type(8))) __bf16 bf16x8;
typedef __attribute__((ext_vector_type(4))) float f32x4;

// ---------------------------------------------------------------------------
// Truncation-based Dekker split: hi = top-16-bits of x, lo = top-16 of (x-hi).
__device__ __forceinline__ __bf16 bf16_bits(unsigned short s) {
    __bf16 r; __builtin_memcpy(&r, &s, 2); return r;
}
__device__ __forceinline__ void split_trunc(float x, __bf16& hi, __bf16& lo) {
    unsigned u = __float_as_uint(x);
    hi = bf16_bits((unsigned short)(u >> 16));
    float l = x - __uint_as_float(u & 0xFFFF0000u);
    lo = bf16_bits((unsigned short)(__float_as_uint(l) >> 16));
}

// ---------------------------------------------------------------------------
// Fused 5-layer LSTM via bf16 MFMA, hi/lo compensated.
//  - Ring buffer of 24 t-slots: layer l writes slot (4-l)+t, reads ih at
//    (5-l)+t, hh at (4-l)+t-1. Write target is always a dead slot -> ONE
//    __syncthreads per step (R6 needed two). No modulo (max index 23).
//  - Weights/biases pre-scaled by log2e (2*log2e for g-gate rows) so every
//    exp is a bare v_exp_f32 (exp2), neg via src modifier.
//  - Pairwise rcp: 2 gate-pair rcps/unit + 1 shared cell rcp = 15 trans per
//    thread-step (was 20); chains stay shallow (R7's 4-deep chain regressed).
//    No clamps: |z|<=~9*2.9, |c|<=20 -> products < 6e34, finite in fp32.
//  - Thread's two units are ADJACENT (w*8+2q, +1): h stores pack to one b32.
__global__ __launch_bounds__(256, 3)
void lstm5_mfma(const float* __restrict__ accel, const float* __restrict__ gyro,
                const float* __restrict__ aWih0, const float* __restrict__ aWihR,
                const float* __restrict__ aWhh,  const float* __restrict__ aBih,
                const float* __restrict__ aBhh,
                const float* __restrict__ gWih0, const float* __restrict__ gWihR,
                const float* __restrict__ gWhh,  const float* __restrict__ gBih,
                const float* __restrict__ gBhh,
                const float* __restrict__ fc1_w,
                __bf16* __restrict__ w1ah, __bf16* __restrict__ w1al,
                __bf16* __restrict__ Xhi, __bf16* __restrict__ Xlo) {
    const int tid  = threadIdx.x;
    const int w    = tid >> 6;        // wave 0..3
    const int lane = tid & 63;
    const int e    = lane & 15;       // elem (B-frag col / C col)
    const int quad = lane >> 4;       // 0..3
    const int sensor = blockIdx.y;
    const int bbase  = blockIdx.x * 16;

    // ---- merged w1_prep preamble (80 of 2048 blocks; saves a launch).
    //      NOTE: fc weights are NOT log2e-scaled.
    if (sensor == 0 && blockIdx.x < 80) {
        int idx = blockIdx.x * 256 + tid;            // < 20480
        int plane = idx & 63;
        int ks    = (idx >> 6) % 40;
        int mt    = idx / (64 * 40);
        int row   = mt * 16 + (plane & 15);
        int col0  = ks * 32 + (plane >> 4) * 8;
        const float* src = fc1_w + row * 1280 + col0;
#pragma unroll
        for (int j = 0; j < 8; ++j) {
            __bf16 h_, l_;
            split_trunc(src[j], h_, l_);
            w1ah[(size_t)idx * 8 + j] = h_;
            w1al[(size_t)idx * 8 + j] = l_;
        }
    }

    const float* xin  = sensor ? gyro  : accel;
    const float* Wih0 = sensor ? gWih0 : aWih0;
    const float* WihR = sensor ? gWihR : aWihR;
    const float* Whh  = sensor ? gWhh  : aWhh;
    const float* Bih  = sensor ? gBih  : aBih;
    const float* Bhh  = sensor ? gBhh  : aBhh;

    __shared__ __align__(16) __bf16 shi[24 * 512];    // ring [slot][chunk][e][j]
    __shared__ __align__(16) __bf16 slo[24 * 512];

    // adjacent units per thread: j = 2*quad, 2*quad+1 within chunk w
    const int ug0 = w * 8 + 2 * quad;
    const int ug1 = w * 8 + 2 * quad + 1;

    // A-frag row m -> (u_local = m>>2, gate = m&3); unit = w*8 + 2*u_local (+1)
    const int m_row   = lane & 15;
    const int orow_t0 = (m_row & 3) * 32 + (w * 8 + 2 * (m_row >> 2));
    const int orow_t1 = orow_t0 + 1;
    const float sA = ((m_row & 3) == 2) ? TWOLOG2E : LOG2E;   // g-gate rows 2x

    bf16x8 wih_h0, wih_l0, wih_h1, wih_l1;
    bf16x8 whh_h0, whh_l0, whh_h1, whh_l1;
    f32x4  bias0v, bias1v;
    float  c0 = 0.f, c1 = 0.f;

#define LOAD_FRAG(Wsrc, orow, fh, fl)                         \
    {                                                         \
        const float* p_ = (Wsrc) + (orow) * 32 + quad * 8;    \
        _Pragma("unroll")                                     \
        for (int jj = 0; jj < 8; ++jj) {                      \
            __bf16 h_, l_;                                    \
            split_trunc(p_[jj] * sA, h_, l_);                 \
            (fh)[jj] = h_;  (fl)[jj] = l_;                    \
        }                                                     \
    }

#define LOAD_BIAS(l)                                                        \
    {                                                                       \
        _Pragma("unroll")                                                   \
        for (int r = 0; r < 4; ++r) {                                       \
            float sc = (r == 2) ? TWOLOG2E : LOG2E;                         \
            bias0v[r] = (Bih[(l) * 128 + r * 32 + ug0] + Bhh[(l) * 128 + r * 32 + ug0]) * sc; \
            bias1v[r] = (Bih[(l) * 128 + r * 32 + ug1] + Bhh[(l) * 128 + r * 32 + ug1]) * sc; \
        }                                                                   \
    }

    // acc* are pre-scaled by log2e (2log2e for g) -> bare exp2 ops.
    // sigmoid pair shares one rcp; (g,o) pair shares one; cell pair shares one.
#define ACT_STORE(wslot)                                                    \
    {                                                                       \
        float d1 = 1.f + __builtin_exp2f(-acc0[0]);                         \
        float d2 = 1.f + __builtin_exp2f(-acc0[1]);                         \
        float d3 = 1.f + __builtin_exp2f( acc0[2]);                         \
        float d4 = 1.f + __builtin_exp2f(-acc0[3]);                         \
        float R12 = __builtin_amdgcn_rcpf(d1 * d2);                         \
        float R34 = __builtin_amdgcn_rcpf(d3 * d4);                         \
        float i0 = R12 * d2, f0 = R12 * d1;                                 \
        float g0 = fmaf(-2.f, R34 * d4, 1.f);                               \
        float o0 = R34 * d3;                                                \
        c0 = fmaf(f0, c0, i0 * g0);                                         \
        float e1 = 1.f + __builtin_exp2f(-acc1[0]);                         \
        float e2 = 1.f + __builtin_exp2f(-acc1[1]);                         \
        float e3 = 1.f + __builtin_exp2f( acc1[2]);                         \
        float e4 = 1.f + __builtin_exp2f(-acc1[3]);                         \
        float S12 = __builtin_amdgcn_rcpf(e1 * e2);                         \
        float S34 = __builtin_amdgcn_rcpf(e3 * e4);                         \
        float i1 = S12 * e2, f1 = S12 * e1;                                 \
        float g1 = fmaf(-2.f, S34 * e4, 1.f);                               \
        float o1 = S34 * e3;                                                \
        c1 = fmaf(f1, c1, i1 * g1);                                         \
        float d9 = 1.f + __builtin_exp2f(c0 * TWOLOG2E);                    \
        float da = 1.f + __builtin_exp2f(c1 * TWOLOG2E);                    \
        float Rc = __builtin_amdgcn_rcpf(d9 * da);                          \
        float h0 = fmaf(-2.f * o0, Rc * da, o0);                            \
        float h1 = fmaf(-2.f * o1, Rc * d9, o1);                            \
        unsigned u0 = __float_as_uint(h0), u1 = __float_as_uint(h1);        \
        float l0 = h0 - __uint_as_float(u0 & 0xFFFF0000u);                  \
        float l1 = h1 - __uint_as_float(u1 & 0xFFFF0000u);                  \
        int ix = (wslot) * 512 + w * 128 + e * 8 + 2 * quad;                \
        *(unsigned*)(shi + ix) = (u0 >> 16) | (u1 & 0xFFFF0000u);           \
        *(unsigned*)(slo + ix) = (__float_as_uint(l0) >> 16) |              \
                                 (__float_as_uint(l1) & 0xFFFF0000u);       \
        __syncthreads();   /* single per-step barrier (ring makes write slot dead) */ \
    }

    // ================= layer 0 (o=4; ih is K=3, done in VALU) ============
    {
        LOAD_FRAG(Whh, orow_t0, whh_h0, whh_l0);
        LOAD_FRAG(Whh, orow_t1, whh_h1, whh_l1);
        LOAD_BIAS(0);
        float w0reg[2][4][3];
#pragma unroll
        for (int r = 0; r < 4; ++r) {
            float sc = (r == 2) ? TWOLOG2E : LOG2E;
#pragma unroll
            for (int k = 0; k < 3; ++k) {
                w0reg[0][r][k] = Wih0[(r * 32 + ug0) * 3 + k] * sc;
                w0reg[1][r][k] = Wih0[(r * 32 + ug1) * 3 + k] * sc;
            }
        }
        const float* xrow = xin + (size_t)(bbase + e) * (T_STEPS * 3);

        for (int t = 0; t < T_STEPS; ++t) {
            float x0 = xrow[t * 3 + 0];
            float x1 = xrow[t * 3 + 1];
            float x2 = xrow[t * 3 + 2];
            f32x4 acc0 = bias0v;
            f32x4 acc1 = bias1v;
#pragma unroll
            for (int r = 0; r < 4; ++r) {
                acc0[r] = fmaf(w0reg[0][r][0], x0,
                          fmaf(w0reg[0][r][1], x1,
                          fmaf(w0reg[0][r][2], x2, acc0[r])));
                acc1[r] = fmaf(w0reg[1][r][0], x0,
                          fmaf(w0reg[1][r][1], x1,
                          fmaf(w0reg[1][r][2], x2, acc1[r])));
            }
            if (t > 0) {
                int rb = (4 + t - 1) * 512 + quad * 128 + e * 8;
                bf16x8 bh = *(const bf16x8*)&shi[rb];
                bf16x8 bl = *(const bf16x8*)&slo[rb];
                acc0 = __builtin_amdgcn_mfma_f32_16x16x32_bf16(whh_h0, bh, acc0, 0, 0, 0);
                acc0 = __builtin_amdgcn_mfma_f32_16x16x32_bf16(whh_h0, bl, acc0, 0, 0, 0);
                acc0 = __builtin_amdgcn_mfma_f32_16x16x32_bf16(whh_l0, bh, acc0, 0, 0, 0);
                acc1 = __builtin_amdgcn_mfma_f32_16x16x32_bf16(whh_h1, bh, acc1, 0, 0, 0);
                acc1 = __builtin_amdgcn_mfma_f32_16x16x32_bf16(whh_h1, bl, acc1, 0, 0, 0);
                acc1 = __builtin_amdgcn_mfma_f32_16x16x32_bf16(whh_l1, bh, acc1, 0, 0, 0);
            }
            ACT_STORE(4 + t);
        }
    }

    // ================= layers 1..4 (o = 4-l) =============================
    for (int l = 1; l < 5; ++l) {
        const int o = 4 - l;
        const float* Wi = WihR + (l - 1) * 4096;
        const float* Wh = Whh + l * 4096;
        LOAD_FRAG(Wi, orow_t0, wih_h0, wih_l0);
        LOAD_FRAG(Wi, orow_t1, wih_h1, wih_l1);
        LOAD_FRAG(Wh, orow_t0, whh_h0, whh_l0);
        LOAD_FRAG(Wh, orow_t1, whh_h1, whh_l1);
        LOAD_BIAS(l);
        c0 = 0.f; c1 = 0.f;

        for (int t = 0; t < T_STEPS; ++t) {
            f32x4 acc0, acc1;
            {   // ih: prev layer h(t) at slot (o+1)+t; bias rides as C
                int rb = (o + 1 + t) * 512 + quad * 128 + e * 8;
                bf16x8 bh = *(const bf16x8*)&shi[rb];
                bf16x8 bl = *(const bf16x8*)&slo[rb];
                acc0 = __builtin_amdgcn_mfma_f32_16x16x32_bf16(wih_h0, bh, bias0v, 0, 0, 0);
                acc0 = __builtin_amdgcn_mfma_f32_16x16x32_bf16(wih_h0, bl, acc0, 0, 0, 0);
                acc0 = __builtin_amdgcn_mfma_f32_16x16x32_bf16(wih_l0, bh, acc0, 0, 0, 0);
                acc1 = __builtin_amdgcn_mfma_f32_16x16x32_bf16(wih_h1, bh, bias1v, 0, 0, 0);
                acc1 = __builtin_amdgcn_mfma_f32_16x16x32_bf16(wih_h1, bl, acc1, 0, 0, 0);
                acc1 = __builtin_amdgcn_mfma_f32_16x16x32_bf16(wih_l1, bh, acc1, 0, 0, 0);
            }
            if (t > 0) {
                int rb = (o + t - 1) * 512 + quad * 128 + e * 8;
                bf16x8 bh = *(const bf16x8*)&shi[rb];
                bf16x8 bl = *(const bf16x8*)&slo[rb];
                acc0 = __builtin_amdgcn_mfma_f32_16x16x32_bf16(whh_h0, bh, acc0, 0, 0, 0);
                acc0 = __builtin_amdgcn_mfma_f32_16x16x32_bf16(whh_h0, bl, acc0, 0, 0, 0);
                acc0 = __builtin_amdgcn_mfma_f32_16x16x32_bf16(whh_l0, bh, acc0, 0, 0, 0);
                acc1 = __builtin_amdgcn_mfma_f32_16x16x32_bf16(whh_h1, bh, acc1, 0, 0, 0);
                acc1 = __builtin_amdgcn_mfma_f32_16x16x32_bf16(whh_h1, bl, acc1, 0, 0, 0);
                acc1 = __builtin_amdgcn_mfma_f32_16x16x32_bf16(whh_l1, bh, acc1, 0, 0, 0);
            }
            ACT_STORE(o + t);
        }
    }

    // ---- epilogue: layer 4 (o=0) seq sits at slots 0..19 -> raw copy ----
    {
        size_t base = ((size_t)(sensor * NGRP + blockIdx.x)) * (20 * 512);
        float4* dh = (float4*)(Xhi + base);
        float4* dl = (float4*)(Xlo + base);
        const float4* sh = (const float4*)shi;
        const float4* sl = (const float4*)slo;
        for (int i = tid; i < 20 * 512 / 8; i += 256) { dh[i] = sh[i]; dl[i] = sl[i]; }
    }
#undef LOAD_FRAG
#undef LOAD_BIAS
#undef ACT_STORE
}

// ---------------------------------------------------------------------------
// Fused fc1+ReLU+fc2 (unchanged from R7). 512 blocks x 256 thr (4 waves).
// wave = (kv K-half, mv m-half); A-frags read once per block.
__global__ __launch_bounds__(256, 2)
void fc_mfma(const __bf16* __restrict__ Xhi, const __bf16* __restrict__ Xlo,
             const __bf16* __restrict__ w1ah, const __bf16* __restrict__ w1al,
             const float* __restrict__ fc1_b, const float* __restrict__ fc2_w,
             const float* __restrict__ fc2_b, float* __restrict__ out) {
    const int tid  = threadIdx.x;
    const int wv   = tid >> 6;
    const int lane = tid & 63;
    const int e    = lane & 15;
    const int quad = lane >> 4;
    const int kv   = wv & 1;         // K half (== sensor)
    const int mv   = wv >> 1;        // m half (4 m-tiles)
    const int g0   = blockIdx.x * 2; // two 16-col groups

    __shared__ __align__(16) f32x4 sacc[2][4][2][64];   // [mv][m][cg][lane] 16KB
    __shared__ float sred[2][2][16][5];                 // [mv][cg][e][n]

    f32x4 acc[4][2];
#pragma unroll
    for (int m = 0; m < 4; ++m)
#pragma unroll
        for (int cg = 0; cg < 2; ++cg) acc[m][cg] = (f32x4){0.f, 0.f, 0.f, 0.f};

    for (int kk = 0; kk < 20; ++kk) {
        int ks = kv * 20 + kk;
        bf16x8 bh[2], bl[2];
#pragma unroll
        for (int cg = 0; cg < 2; ++cg) {
            size_t bb = ((size_t)(kv * NGRP + g0 + cg)) * (20 * 512) + kk * 512 + lane * 8;
            bh[cg] = *(const bf16x8*)(Xhi + bb);
            bl[cg] = *(const bf16x8*)(Xlo + bb);
        }
#pragma unroll
        for (int m = 0; m < 4; ++m) {
            int mt = mv * 4 + m;
            size_t ab = ((size_t)((mt * 40 + ks) * 64 + lane)) * 8;
            bf16x8 ah = *(const bf16x8*)(w1ah + ab);
            bf16x8 al = *(const bf16x8*)(w1al + ab);
#pragma unroll
            for (int cg = 0; cg < 2; ++cg) {
                acc[m][cg] = __builtin_amdgcn_mfma_f32_16x16x32_bf16(ah, bh[cg], acc[m][cg], 0, 0, 0);
                acc[m][cg] = __builtin_amdgcn_mfma_f32_16x16x32_bf16(ah, bl[cg], acc[m][cg], 0, 0, 0);
                acc[m][cg] = __builtin_amdgcn_mfma_f32_16x16x32_bf16(al, bh[cg], acc[m][cg], 0, 0, 0);
            }
        }
    }

    if (kv == 1) {
#pragma unroll
        for (int m = 0; m < 4; ++m)
#pragma unroll
            for (int cg = 0; cg < 2; ++cg) sacc[mv][m][cg][lane] = acc[m][cg];
    }
    __syncthreads();

    if (kv == 0) {
        float p[2][5];
#pragma unroll
        for (int cg = 0; cg < 2; ++cg)
#pragma unroll
            for (int n = 0; n < 5; ++n) p[cg][n] = 0.f;
#pragma unroll
        for (int m = 0; m < 4; ++m) {
            int mt = mv * 4 + m;
#pragma unroll
            for (int cg = 0; cg < 2; ++cg) {
                f32x4 z  = acc[m][cg];
                f32x4 zz = sacc[mv][m][cg][lane];
#pragma unroll
                for (int r = 0; r < 4; ++r) {
                    int row = mt * 16 + quad * 4 + r;   // C row = quad*4 + reg
                    float v = fmaxf(z[r] + zz[r] + fc1_b[row], 0.f);
#pragma unroll
                    for (int n = 0; n < 5; ++n)
                        p[cg][n] = fmaf(v, fc2_w[n * 128 + row], p[cg][n]);
                }
            }
        }
#pragma unroll
        for (int cg = 0; cg < 2; ++cg)
#pragma unroll
            for (int n = 0; n < 5; ++n) {
                p[cg][n] += __shfl_xor(p[cg][n], 16, 64);
                p[cg][n] += __shfl_xor(p[cg][n], 32, 64);
            }
        if (quad == 0) {
#pragma unroll
            for (int cg = 0; cg < 2; ++cg)
#pragma unroll
                for (int n = 0; n < 5; ++n) sred[mv][cg][e][n] = p[cg][n];
        }
    }
    __syncthreads();
    if (tid < 160) {
        int col = tid / 5, n = tid - col * 5;           // col 0..31
        out[((size_t)(blockIdx.x * 32 + col)) * 5 + n] =
            sred[0][col >> 4][col & 15][n] + sred[1][col >> 4][col & 15][n] + fc2_b[n];
    }
}

// ---------------------------------------------------------------------------
extern "C" void kernel_launch(void* const* d_in, const int* in_sizes, int n_in,
                              void* d_out, int out_size, void* d_ws, size_t ws_size,
                              hipStream_t stream) {
    const float* accel  = (const float*)d_in[0];
    const float* gyro   = (const float*)d_in[1];
    const float* aWih0  = (const float*)d_in[2];
    const float* aWihR  = (const float*)d_in[3];
    const float* aWhh   = (const float*)d_in[4];
    const float* aBih   = (const float*)d_in[5];
    const float* aBhh   = (const float*)d_in[6];
    const float* gWih0  = (const float*)d_in[7];
    const float* gWihR  = (const float*)d_in[8];
    const float* gWhh   = (const float*)d_in[9];
    const float* gBih   = (const float*)d_in[10];
    const float* gBhh   = (const float*)d_in[11];
    const float* fc1_w  = (const float*)d_in[12];
    const float* fc1_b  = (const float*)d_in[13];
    const float* fc2_w  = (const float*)d_in[14];
    const float* fc2_b  = (const float*)d_in[15];
    float* out = (float*)d_out;

    const size_t XN = (size_t)2 * NGRP * 20 * 512;    // 20,971,520 bf16 each
    __bf16* Xhi  = (__bf16*)d_ws;
    __bf16* Xlo  = Xhi + XN;
    __bf16* W1ah = Xlo + XN;                          // 163,840 bf16 each
    __bf16* W1al = W1ah + 163840;

    hipLaunchKernelGGL(lstm5_mfma, dim3(NGRP, 2), dim3(256), 0, stream,
                       accel, gyro, aWih0, aWihR, aWhh, aBih, aBhh,
                       gWih0, gWihR, gWhh, gBih, gBhh,
                       fc1_w, W1ah, W1al, Xhi, Xlo);

    hipLaunchKernelGGL(fc_mfma, dim3(B_TOTAL / 32), dim3(256), 0, stream,
                       Xhi, Xlo, W1ah, W1al, fc1_b, fc2_w, fc2_b, out);
}

// Round 9
// 327.522 us; speedup vs baseline: 1.0616x; 1.0616x over previous
//
#include <hip/hip_runtime.h>
#include <math.h>

#define B_TOTAL 16384
#define T_STEPS 20
#define NGRP    1024            // B_TOTAL/16 batch groups per sensor

typedef __attribute__((ext_vector_type(8))) __bf16 bf16x8;
typedef __attribute__((ext_vector_type(4))) float f32x4;

// ---------------------------------------------------------------------------
__device__ __forceinline__ float sigf(float x) {
    return __builtin_amdgcn_rcpf(1.0f + __expf(-x));
}
__device__ __forceinline__ float tanhf_fast(float x) {
    return fmaf(-2.0f, __builtin_amdgcn_rcpf(__expf(2.0f * x) + 1.0f), 1.0f);
}

// Truncation-based Dekker split: hi = top-16-bits of x, lo = top-16 of (x-hi).
__device__ __forceinline__ __bf16 bf16_bits(unsigned short s) {
    __bf16 r; __builtin_memcpy(&r, &s, 2); return r;
}
__device__ __forceinline__ void split_trunc(float x, __bf16& hi, __bf16& lo) {
    unsigned u = __float_as_uint(x);
    hi = bf16_bits((unsigned short)(u >> 16));
    float l = x - __uint_as_float(u & 0xFFFF0000u);
    lo = bf16_bits((unsigned short)(__float_as_uint(l) >> 16));
}

// ---------------------------------------------------------------------------
// Fused 5-layer LSTM via bf16 MFMA, hi/lo compensated.
// EXACT R6 kernel (205 us, VALU 70%, MFMA 30%): R7's deep-chain rcp batching
// and R8's ring/packed-store variants both regressed — this structure is the
// measured local optimum; do not micro-tune it without counter evidence.
__global__ __launch_bounds__(256, 4)
void lstm5_mfma(const float* __restrict__ accel, const float* __restrict__ gyro,
                const float* __restrict__ aWih0, const float* __restrict__ aWihR,
                const float* __restrict__ aWhh,  const float* __restrict__ aBih,
                const float* __restrict__ aBhh,
                const float* __restrict__ gWih0, const float* __restrict__ gWihR,
                const float* __restrict__ gWhh,  const float* __restrict__ gBih,
                const float* __restrict__ gBhh,
                __bf16* __restrict__ Xhi, __bf16* __restrict__ Xlo) {
    const int tid  = threadIdx.x;
    const int w    = tid >> 6;        // wave 0..3
    const int lane = tid & 63;
    const int e    = lane & 15;       // elem (B-frag col / C col)
    const int quad = lane >> 4;       // 0..3
    const int sensor = blockIdx.y;
    const int bbase  = blockIdx.x * 16;

    const float* xin  = sensor ? gyro  : accel;
    const float* Wih0 = sensor ? gWih0 : aWih0;
    const float* WihR = sensor ? gWihR : aWihR;
    const float* Whh  = sensor ? gWhh  : aWhh;
    const float* Bih  = sensor ? gBih  : aBih;
    const float* Bhh  = sensor ? gBhh  : aBhh;

    __shared__ __align__(16) __bf16 shi[20 * 512];    // [t][chunk][e][j]
    __shared__ __align__(16) __bf16 slo[20 * 512];

    const int ug0 = w * 8 + quad;        // tile 0 unit
    const int ug1 = w * 8 + 4 + quad;    // tile 1 unit

    const int m_row   = lane & 15;
    const int orow_t0 = (m_row & 3) * 32 + (w * 8 + (m_row >> 2));
    const int orow_t1 = (m_row & 3) * 32 + (w * 8 + 4 + (m_row >> 2));

    bf16x8 wih_h0, wih_l0, wih_h1, wih_l1;
    bf16x8 whh_h0, whh_l0, whh_h1, whh_l1;
    f32x4  bias0v, bias1v;
    float  c0 = 0.f, c1 = 0.f;

#define LOAD_FRAG(Wsrc, orow, fh, fl)                         \
    {                                                         \
        const float* p_ = (Wsrc) + (orow) * 32 + quad * 8;    \
        _Pragma("unroll")                                     \
        for (int jj = 0; jj < 8; ++jj) {                      \
            __bf16 h_, l_;                                    \
            split_trunc(p_[jj], h_, l_);                      \
            (fh)[jj] = h_;  (fl)[jj] = l_;                    \
        }                                                     \
    }

#define LOAD_BIAS(l)                                                        \
    {                                                                       \
        _Pragma("unroll")                                                   \
        for (int r = 0; r < 4; ++r) {                                       \
            bias0v[r] = Bih[(l) * 128 + r * 32 + ug0] + Bhh[(l) * 128 + r * 32 + ug0]; \
            bias1v[r] = Bih[(l) * 128 + r * 32 + ug1] + Bhh[(l) * 128 + r * 32 + ug1]; \
        }                                                                   \
    }

#define ACT_STORE(t)                                                        \
    {                                                                       \
        float i0 = sigf(acc0[0]), f0 = sigf(acc0[1]);                       \
        float g0 = tanhf_fast(acc0[2]), o0 = sigf(acc0[3]);                 \
        c0 = f0 * c0 + i0 * g0;                                             \
        float h0 = o0 * tanhf_fast(c0);                                     \
        float i1 = sigf(acc1[0]), f1 = sigf(acc1[1]);                       \
        float g1 = tanhf_fast(acc1[2]), o1 = sigf(acc1[3]);                 \
        c1 = f1 * c1 + i1 * g1;                                             \
        float h1 = o1 * tanhf_fast(c1);                                     \
        __syncthreads();  /* all waves done reading shi/slo[t] */           \
        int i0x = (t) * 512 + w * 128 + e * 8 + quad;                       \
        int i1x = i0x + 4;                                                  \
        __bf16 hh_, ll_;                                                    \
        split_trunc(h0, hh_, ll_);  shi[i0x] = hh_;  slo[i0x] = ll_;        \
        split_trunc(h1, hh_, ll_);  shi[i1x] = hh_;  slo[i1x] = ll_;        \
        __syncthreads();  /* writes visible before next step's reads */     \
    }

    // ================= layer 0 (ih is K=3, done in VALU) =================
    {
        LOAD_FRAG(Whh, orow_t0, whh_h0, whh_l0);
        LOAD_FRAG(Whh, orow_t1, whh_h1, whh_l1);
        LOAD_BIAS(0);
        float w0reg[2][4][3];
#pragma unroll
        for (int r = 0; r < 4; ++r)
#pragma unroll
            for (int k = 0; k < 3; ++k) {
                w0reg[0][r][k] = Wih0[(r * 32 + ug0) * 3 + k];
                w0reg[1][r][k] = Wih0[(r * 32 + ug1) * 3 + k];
            }
        const float* xrow = xin + (size_t)(bbase + e) * (T_STEPS * 3);

        for (int t = 0; t < T_STEPS; ++t) {
            float x0 = xrow[t * 3 + 0];
            float x1 = xrow[t * 3 + 1];
            float x2 = xrow[t * 3 + 2];
            f32x4 acc0 = bias0v;
            f32x4 acc1 = bias1v;
#pragma unroll
            for (int r = 0; r < 4; ++r) {
                acc0[r] = fmaf(w0reg[0][r][0], x0,
                          fmaf(w0reg[0][r][1], x1,
                          fmaf(w0reg[0][r][2], x2, acc0[r])));
                acc1[r] = fmaf(w0reg[1][r][0], x0,
                          fmaf(w0reg[1][r][1], x1,
                          fmaf(w0reg[1][r][2], x2, acc1[r])));
            }
            if (t > 0) {
                int rb = (t - 1) * 512 + quad * 128 + e * 8;
                bf16x8 bh = *(const bf16x8*)&shi[rb];
                bf16x8 bl = *(const bf16x8*)&slo[rb];
                acc0 = __builtin_amdgcn_mfma_f32_16x16x32_bf16(whh_h0, bh, acc0, 0, 0, 0);
                acc0 = __builtin_amdgcn_mfma_f32_16x16x32_bf16(whh_h0, bl, acc0, 0, 0, 0);
                acc0 = __builtin_amdgcn_mfma_f32_16x16x32_bf16(whh_l0, bh, acc0, 0, 0, 0);
                acc1 = __builtin_amdgcn_mfma_f32_16x16x32_bf16(whh_h1, bh, acc1, 0, 0, 0);
                acc1 = __builtin_amdgcn_mfma_f32_16x16x32_bf16(whh_h1, bl, acc1, 0, 0, 0);
                acc1 = __builtin_amdgcn_mfma_f32_16x16x32_bf16(whh_l1, bh, acc1, 0, 0, 0);
            }
            ACT_STORE(t);
        }
    }

    // ================= layers 1..4 (both projections via MFMA) ===========
    for (int l = 1; l < 5; ++l) {
        const float* Wi = WihR + (l - 1) * 4096;
        const float* Wh = Whh + l * 4096;
        LOAD_FRAG(Wi, orow_t0, wih_h0, wih_l0);
        LOAD_FRAG(Wi, orow_t1, wih_h1, wih_l1);
        LOAD_FRAG(Wh, orow_t0, whh_h0, whh_l0);
        LOAD_FRAG(Wh, orow_t1, whh_h1, whh_l1);
        LOAD_BIAS(l);
        c0 = 0.f; c1 = 0.f;

        for (int t = 0; t < T_STEPS; ++t) {
            f32x4 acc0, acc1;
            {   // ih: x = h_{l-1}(t); bias rides in as C of first MFMA
                int rb = t * 512 + quad * 128 + e * 8;
                bf16x8 bh = *(const bf16x8*)&shi[rb];
                bf16x8 bl = *(const bf16x8*)&slo[rb];
                acc0 = __builtin_amdgcn_mfma_f32_16x16x32_bf16(wih_h0, bh, bias0v, 0, 0, 0);
                acc0 = __builtin_amdgcn_mfma_f32_16x16x32_bf16(wih_h0, bl, acc0, 0, 0, 0);
                acc0 = __builtin_amdgcn_mfma_f32_16x16x32_bf16(wih_l0, bh, acc0, 0, 0, 0);
                acc1 = __builtin_amdgcn_mfma_f32_16x16x32_bf16(wih_h1, bh, bias1v, 0, 0, 0);
                acc1 = __builtin_amdgcn_mfma_f32_16x16x32_bf16(wih_h1, bl, acc1, 0, 0, 0);
                acc1 = __builtin_amdgcn_mfma_f32_16x16x32_bf16(wih_l1, bh, acc1, 0, 0, 0);
            }
            if (t > 0) {
                int rb = (t - 1) * 512 + quad * 128 + e * 8;
                bf16x8 bh = *(const bf16x8*)&shi[rb];
                bf16x8 bl = *(const bf16x8*)&slo[rb];
                acc0 = __builtin_amdgcn_mfma_f32_16x16x32_bf16(whh_h0, bh, acc0, 0, 0, 0);
                acc0 = __builtin_amdgcn_mfma_f32_16x16x32_bf16(whh_h0, bl, acc0, 0, 0, 0);
                acc0 = __builtin_amdgcn_mfma_f32_16x16x32_bf16(whh_l0, bh, acc0, 0, 0, 0);
                acc1 = __builtin_amdgcn_mfma_f32_16x16x32_bf16(whh_h1, bh, acc1, 0, 0, 0);
                acc1 = __builtin_amdgcn_mfma_f32_16x16x32_bf16(whh_h1, bl, acc1, 0, 0, 0);
                acc1 = __builtin_amdgcn_mfma_f32_16x16x32_bf16(whh_l1, bh, acc1, 0, 0, 0);
            }
            ACT_STORE(t);
        }
    }
    __syncthreads();

    // ---- epilogue: raw copy of frag-layout hi/lo to global for fc ----
    {
        size_t base = ((size_t)(sensor * NGRP + blockIdx.x)) * (20 * 512);
        float4* dh = (float4*)(Xhi + base);
        float4* dl = (float4*)(Xlo + base);
        const float4* sh = (const float4*)shi;
        const float4* sl = (const float4*)slo;
        for (int i = tid; i < 20 * 512 / 8; i += 256) { dh[i] = sh[i]; dl[i] = sl[i]; }
    }
#undef LOAD_FRAG
#undef LOAD_BIAS
#undef ACT_STORE
}

// ---------------------------------------------------------------------------
// fc1_w [128][1280] -> MFMA A-frag hi/lo arrays: [mt 0..7][ks 0..39][lane][8]
__global__ void w1_prep(const float* __restrict__ w1,
                        __bf16* __restrict__ w1ah, __bf16* __restrict__ w1al) {
    int t = blockIdx.x * blockDim.x + threadIdx.x;     // 8*40*64 = 20480
    if (t >= 20480) return;
    int lane = t & 63;
    int ks   = (t >> 6) % 40;
    int mt   = t / (64 * 40);
    int row  = mt * 16 + (lane & 15);
    int col0 = ks * 32 + (lane >> 4) * 8;
    const float* src = w1 + row * 1280 + col0;
#pragma unroll
    for (int j = 0; j < 8; ++j) {
        __bf16 h_, l_;
        split_trunc(src[j], h_, l_);
        w1ah[t * 8 + j] = h_;
        w1al[t * 8 + j] = l_;
    }
}

// ---------------------------------------------------------------------------
// Fused fc1+ReLU+fc2, latency-tuned: 1024 blocks x 128 thr (2 waves).
// wave = K-half (sensor); each wave does all 8 m-tiles for its 20 ks.
// 8 blocks/CU -> 16 waves/CU (2x R7's TLP for load-latency hiding); kk loop
// unrolled x2 so two iterations' ~18 L2 loads are in flight per MFMA cluster.
__global__ __launch_bounds__(128, 4)
void fc_mfma(const __bf16* __restrict__ Xhi, const __bf16* __restrict__ Xlo,
             const __bf16* __restrict__ w1ah, const __bf16* __restrict__ w1al,
             const float* __restrict__ fc1_b, const float* __restrict__ fc2_w,
             const float* __restrict__ fc2_b, float* __restrict__ out) {
    const int tid  = threadIdx.x;
    const int kv   = tid >> 6;       // K half (== sensor)
    const int lane = tid & 63;
    const int e    = lane & 15;
    const int quad = lane >> 4;
    const int g    = blockIdx.x;     // batch group (16 cols)

    __shared__ __align__(16) f32x4 sacc[8][64];    // kv==1 partials, 8 KB
    __shared__ float sred[16][5];

    f32x4 acc[8];
#pragma unroll
    for (int m = 0; m < 8; ++m) acc[m] = (f32x4){0.f, 0.f, 0.f, 0.f};

    const __bf16* bh_base = Xhi + ((size_t)(kv * NGRP + g)) * (20 * 512) + lane * 8;
    const __bf16* bl_base = Xlo + ((size_t)(kv * NGRP + g)) * (20 * 512) + lane * 8;

#pragma unroll 2
    for (int kk = 0; kk < 20; ++kk) {
        int ks = kv * 20 + kk;
        bf16x8 bh = *(const bf16x8*)(bh_base + kk * 512);
        bf16x8 bl = *(const bf16x8*)(bl_base + kk * 512);
#pragma unroll
        for (int m = 0; m < 8; ++m) {
            size_t ab = ((size_t)((m * 40 + ks) * 64 + lane)) * 8;
            bf16x8 ah = *(const bf16x8*)(w1ah + ab);
            bf16x8 al = *(const bf16x8*)(w1al + ab);
            acc[m] = __builtin_amdgcn_mfma_f32_16x16x32_bf16(ah, bh, acc[m], 0, 0, 0);
            acc[m] = __builtin_amdgcn_mfma_f32_16x16x32_bf16(ah, bl, acc[m], 0, 0, 0);
            acc[m] = __builtin_amdgcn_mfma_f32_16x16x32_bf16(al, bh, acc[m], 0, 0, 0);
        }
    }

    if (kv == 1) {
#pragma unroll
        for (int m = 0; m < 8; ++m) sacc[m][lane] = acc[m];
    }
    __syncthreads();

    if (kv == 0) {
        float p[5] = {0.f, 0.f, 0.f, 0.f, 0.f};
#pragma unroll
        for (int m = 0; m < 8; ++m) {
            f32x4 zz = sacc[m][lane];
#pragma unroll
            for (int r = 0; r < 4; ++r) {
                int row = m * 16 + quad * 4 + r;        // C row = quad*4 + reg
                float v = fmaxf(acc[m][r] + zz[r] + fc1_b[row], 0.f);
#pragma unroll
                for (int n = 0; n < 5; ++n) p[n] = fmaf(v, fc2_w[n * 128 + row], p[n]);
            }
        }
#pragma unroll
        for (int n = 0; n < 5; ++n) {
            p[n] += __shfl_xor(p[n], 16, 64);
            p[n] += __shfl_xor(p[n], 32, 64);
        }
        if (quad == 0) {
#pragma unroll
            for (int n = 0; n < 5; ++n) sred[e][n] = p[n];
        }
    }
    __syncthreads();
    if (tid < 80) {
        int col = tid / 5, n = tid - col * 5;
        out[((size_t)(g * 16 + col)) * 5 + n] = sred[col][n] + fc2_b[n];
    }
}

// ---------------------------------------------------------------------------
extern "C" void kernel_launch(void* const* d_in, const int* in_sizes, int n_in,
                              void* d_out, int out_size, void* d_ws, size_t ws_size,
                              hipStream_t stream) {
    const float* accel  = (const float*)d_in[0];
    const float* gyro   = (const float*)d_in[1];
    const float* aWih0  = (const float*)d_in[2];
    const float* aWihR  = (const float*)d_in[3];
    const float* aWhh   = (const float*)d_in[4];
    const float* aBih   = (const float*)d_in[5];
    const float* aBhh   = (const float*)d_in[6];
    const float* gWih0  = (const float*)d_in[7];
    const float* gWihR  = (const float*)d_in[8];
    const float* gWhh   = (const float*)d_in[9];
    const float* gBih   = (const float*)d_in[10];
    const float* gBhh   = (const float*)d_in[11];
    const float* fc1_w  = (const float*)d_in[12];
    const float* fc1_b  = (const float*)d_in[13];
    const float* fc2_w  = (const float*)d_in[14];
    const float* fc2_b  = (const float*)d_in[15];
    float* out = (float*)d_out;

    const size_t XN = (size_t)2 * NGRP * 20 * 512;    // 20,971,520 bf16 each
    __bf16* Xhi  = (__bf16*)d_ws;
    __bf16* Xlo  = Xhi + XN;
    __bf16* W1ah = Xlo + XN;                          // 163,840 bf16 each
    __bf16* W1al = W1ah + 163840;

    hipLaunchKernelGGL(w1_prep, dim3(80), dim3(256), 0, stream, fc1_w, W1ah, W1al);

    hipLaunchKernelGGL(lstm5_mfma, dim3(NGRP, 2), dim3(256), 0, stream,
                       accel, gyro, aWih0, aWihR, aWhh, aBih, aBhh,
                       gWih0, gWihR, gWhh, gBih, gBhh, Xhi, Xlo);

    hipLaunchKernelGGL(fc_mfma, dim3(NGRP), dim3(128), 0, stream,
                       Xhi, Xlo, W1ah, W1al, fc1_b, fc2_w, fc2_b, out);
}

// Round 10
// 292.550 us; speedup vs baseline: 1.1885x; 1.1195x over previous
//
#include <hip/hip_runtime.h>
#include <math.h>

#define B_TOTAL 16384
#define T_STEPS 20
#define NGRP    1024            // B_TOTAL/16 batch groups per sensor

typedef __attribute__((ext_vector_type(8))) __bf16 bf16x8;
typedef __attribute__((ext_vector_type(4))) float f32x4;

// ---------------------------------------------------------------------------
__device__ __forceinline__ float sigf(float x) {
    return __builtin_amdgcn_rcpf(1.0f + __expf(-x));
}
__device__ __forceinline__ float tanhf_fast(float x) {
    return fmaf(-2.0f, __builtin_amdgcn_rcpf(__expf(2.0f * x) + 1.0f), 1.0f);
}

// Truncation-based Dekker split: hi = top-16-bits of x, lo = top-16 of (x-hi).
__device__ __forceinline__ __bf16 bf16_bits(unsigned short s) {
    __bf16 r; __builtin_memcpy(&r, &s, 2); return r;
}
__device__ __forceinline__ void split_trunc(float x, __bf16& hi, __bf16& lo) {
    unsigned u = __float_as_uint(x);
    hi = bf16_bits((unsigned short)(u >> 16));
    float l = x - __uint_as_float(u & 0xFFFF0000u);
    lo = bf16_bits((unsigned short)(__float_as_uint(l) >> 16));
}

// ---------------------------------------------------------------------------
// Fused 5-layer LSTM via bf16 MFMA, hi/lo compensated — R6 structure (the
// measured local optimum: 210 us) + fc1-partial TAIL. The tail consumes the
// final h-seq directly from LDS (it is already in MFMA B-frag layout) and
// writes only 8 KB of fp32 fc1-partials per block instead of 40 KB of X:
// kills the 84 MB X round-trip AND the standalone fc kernel's latency wall
// (R6/R7/R9 all measured 80-117 us vs ~25 us traffic roofline).
__global__ __launch_bounds__(256, 4)
void lstm5_mfma(const float* __restrict__ accel, const float* __restrict__ gyro,
                const float* __restrict__ aWih0, const float* __restrict__ aWihR,
                const float* __restrict__ aWhh,  const float* __restrict__ aBih,
                const float* __restrict__ aBhh,
                const float* __restrict__ gWih0, const float* __restrict__ gWihR,
                const float* __restrict__ gWhh,  const float* __restrict__ gBih,
                const float* __restrict__ gBhh,
                const __bf16* __restrict__ w1ah, const __bf16* __restrict__ w1al,
                float* __restrict__ Zpart /* [2][NGRP][8][16][16] */) {
    const int tid  = threadIdx.x;
    const int w    = tid >> 6;        // wave 0..3
    const int lane = tid & 63;
    const int e    = lane & 15;       // elem (B-frag col / C col)
    const int quad = lane >> 4;       // 0..3
    const int sensor = blockIdx.y;
    const int bbase  = blockIdx.x * 16;

    const float* xin  = sensor ? gyro  : accel;
    const float* Wih0 = sensor ? gWih0 : aWih0;
    const float* WihR = sensor ? gWihR : aWihR;
    const float* Whh  = sensor ? gWhh  : aWhh;
    const float* Bih  = sensor ? gBih  : aBih;
    const float* Bhh  = sensor ? gBhh  : aBhh;

    __shared__ __align__(16) __bf16 shi[20 * 512];    // [t][chunk][e][j]
    __shared__ __align__(16) __bf16 slo[20 * 512];

    const int ug0 = w * 8 + quad;        // tile 0 unit
    const int ug1 = w * 8 + 4 + quad;    // tile 1 unit

    const int m_row   = lane & 15;
    const int orow_t0 = (m_row & 3) * 32 + (w * 8 + (m_row >> 2));
    const int orow_t1 = (m_row & 3) * 32 + (w * 8 + 4 + (m_row >> 2));

    bf16x8 wih_h0, wih_l0, wih_h1, wih_l1;
    bf16x8 whh_h0, whh_l0, whh_h1, whh_l1;
    f32x4  bias0v, bias1v;
    float  c0 = 0.f, c1 = 0.f;

#define LOAD_FRAG(Wsrc, orow, fh, fl)                         \
    {                                                         \
        const float* p_ = (Wsrc) + (orow) * 32 + quad * 8;    \
        _Pragma("unroll")                                     \
        for (int jj = 0; jj < 8; ++jj) {                      \
            __bf16 h_, l_;                                    \
            split_trunc(p_[jj], h_, l_);                      \
            (fh)[jj] = h_;  (fl)[jj] = l_;                    \
        }                                                     \
    }

#define LOAD_BIAS(l)                                                        \
    {                                                                       \
        _Pragma("unroll")                                                   \
        for (int r = 0; r < 4; ++r) {                                       \
            bias0v[r] = Bih[(l) * 128 + r * 32 + ug0] + Bhh[(l) * 128 + r * 32 + ug0]; \
            bias1v[r] = Bih[(l) * 128 + r * 32 + ug1] + Bhh[(l) * 128 + r * 32 + ug1]; \
        }                                                                   \
    }

#define ACT_STORE(t)                                                        \
    {                                                                       \
        float i0 = sigf(acc0[0]), f0 = sigf(acc0[1]);                       \
        float g0 = tanhf_fast(acc0[2]), o0 = sigf(acc0[3]);                 \
        c0 = f0 * c0 + i0 * g0;                                             \
        float h0 = o0 * tanhf_fast(c0);                                     \
        float i1 = sigf(acc1[0]), f1 = sigf(acc1[1]);                       \
        float g1 = tanhf_fast(acc1[2]), o1 = sigf(acc1[3]);                 \
        c1 = f1 * c1 + i1 * g1;                                             \
        float h1 = o1 * tanhf_fast(c1);                                     \
        __syncthreads();  /* all waves done reading shi/slo[t] */           \
        int i0x = (t) * 512 + w * 128 + e * 8 + quad;                       \
        int i1x = i0x + 4;                                                  \
        __bf16 hh_, ll_;                                                    \
        split_trunc(h0, hh_, ll_);  shi[i0x] = hh_;  slo[i0x] = ll_;        \
        split_trunc(h1, hh_, ll_);  shi[i1x] = hh_;  slo[i1x] = ll_;        \
        __syncthreads();  /* writes visible before next step's reads */     \
    }

    // ================= layer 0 (ih is K=3, done in VALU) =================
    {
        LOAD_FRAG(Whh, orow_t0, whh_h0, whh_l0);
        LOAD_FRAG(Whh, orow_t1, whh_h1, whh_l1);
        LOAD_BIAS(0);
        float w0reg[2][4][3];
#pragma unroll
        for (int r = 0; r < 4; ++r)
#pragma unroll
            for (int k = 0; k < 3; ++k) {
                w0reg[0][r][k] = Wih0[(r * 32 + ug0) * 3 + k];
                w0reg[1][r][k] = Wih0[(r * 32 + ug1) * 3 + k];
            }
        const float* xrow = xin + (size_t)(bbase + e) * (T_STEPS * 3);

        for (int t = 0; t < T_STEPS; ++t) {
            float x0 = xrow[t * 3 + 0];
            float x1 = xrow[t * 3 + 1];
            float x2 = xrow[t * 3 + 2];
            f32x4 acc0 = bias0v;
            f32x4 acc1 = bias1v;
#pragma unroll
            for (int r = 0; r < 4; ++r) {
                acc0[r] = fmaf(w0reg[0][r][0], x0,
                          fmaf(w0reg[0][r][1], x1,
                          fmaf(w0reg[0][r][2], x2, acc0[r])));
                acc1[r] = fmaf(w0reg[1][r][0], x0,
                          fmaf(w0reg[1][r][1], x1,
                          fmaf(w0reg[1][r][2], x2, acc1[r])));
            }
            if (t > 0) {
                int rb = (t - 1) * 512 + quad * 128 + e * 8;
                bf16x8 bh = *(const bf16x8*)&shi[rb];
                bf16x8 bl = *(const bf16x8*)&slo[rb];
                acc0 = __builtin_amdgcn_mfma_f32_16x16x32_bf16(whh_h0, bh, acc0, 0, 0, 0);
                acc0 = __builtin_amdgcn_mfma_f32_16x16x32_bf16(whh_h0, bl, acc0, 0, 0, 0);
                acc0 = __builtin_amdgcn_mfma_f32_16x16x32_bf16(whh_l0, bh, acc0, 0, 0, 0);
                acc1 = __builtin_amdgcn_mfma_f32_16x16x32_bf16(whh_h1, bh, acc1, 0, 0, 0);
                acc1 = __builtin_amdgcn_mfma_f32_16x16x32_bf16(whh_h1, bl, acc1, 0, 0, 0);
                acc1 = __builtin_amdgcn_mfma_f32_16x16x32_bf16(whh_l1, bh, acc1, 0, 0, 0);
            }
            ACT_STORE(t);
        }
    }

    // ================= layers 1..4 (both projections via MFMA) ===========
    for (int l = 1; l < 5; ++l) {
        const float* Wi = WihR + (l - 1) * 4096;
        const float* Wh = Whh + l * 4096;
        LOAD_FRAG(Wi, orow_t0, wih_h0, wih_l0);
        LOAD_FRAG(Wi, orow_t1, wih_h1, wih_l1);
        LOAD_FRAG(Wh, orow_t0, whh_h0, whh_l0);
        LOAD_FRAG(Wh, orow_t1, whh_h1, whh_l1);
        LOAD_BIAS(l);
        c0 = 0.f; c1 = 0.f;

        for (int t = 0; t < T_STEPS; ++t) {
            f32x4 acc0, acc1;
            {   // ih: x = h_{l-1}(t); bias rides in as C of first MFMA
                int rb = t * 512 + quad * 128 + e * 8;
                bf16x8 bh = *(const bf16x8*)&shi[rb];
                bf16x8 bl = *(const bf16x8*)&slo[rb];
                acc0 = __builtin_amdgcn_mfma_f32_16x16x32_bf16(wih_h0, bh, bias0v, 0, 0, 0);
                acc0 = __builtin_amdgcn_mfma_f32_16x16x32_bf16(wih_h0, bl, acc0, 0, 0, 0);
                acc0 = __builtin_amdgcn_mfma_f32_16x16x32_bf16(wih_l0, bh, acc0, 0, 0, 0);
                acc1 = __builtin_amdgcn_mfma_f32_16x16x32_bf16(wih_h1, bh, bias1v, 0, 0, 0);
                acc1 = __builtin_amdgcn_mfma_f32_16x16x32_bf16(wih_h1, bl, acc1, 0, 0, 0);
                acc1 = __builtin_amdgcn_mfma_f32_16x16x32_bf16(wih_l1, bh, acc1, 0, 0, 0);
            }
            if (t > 0) {
                int rb = (t - 1) * 512 + quad * 128 + e * 8;
                bf16x8 bh = *(const bf16x8*)&shi[rb];
                bf16x8 bl = *(const bf16x8*)&slo[rb];
                acc0 = __builtin_amdgcn_mfma_f32_16x16x32_bf16(whh_h0, bh, acc0, 0, 0, 0);
                acc0 = __builtin_amdgcn_mfma_f32_16x16x32_bf16(whh_h0, bl, acc0, 0, 0, 0);
                acc0 = __builtin_amdgcn_mfma_f32_16x16x32_bf16(whh_l0, bh, acc0, 0, 0, 0);
                acc1 = __builtin_amdgcn_mfma_f32_16x16x32_bf16(whh_h1, bh, acc1, 0, 0, 0);
                acc1 = __builtin_amdgcn_mfma_f32_16x16x32_bf16(whh_h1, bl, acc1, 0, 0, 0);
                acc1 = __builtin_amdgcn_mfma_f32_16x16x32_bf16(whh_l1, bh, acc1, 0, 0, 0);
            }
            ACT_STORE(t);
        }
    }
    __syncthreads();

    // ---- fc1-partial tail: Z[sensor-half] = W1[:, half] · X  ------------
    // B-frags read straight from LDS (same addressing as the step loop);
    // A-frags from the pre-split W1 array (L2-resident). wave w covers
    // m-tiles {2w, 2w+1}; C-tile is 16x16 -> 4 fp32/lane per m-tile.
    {
        f32x4 zacc0 = (f32x4){0.f, 0.f, 0.f, 0.f};
        f32x4 zacc1 = (f32x4){0.f, 0.f, 0.f, 0.f};
        const int mt0 = w * 2, mt1 = w * 2 + 1;
        for (int t = 0; t < T_STEPS; ++t) {
            int rb = t * 512 + quad * 128 + e * 8;
            bf16x8 bh = *(const bf16x8*)&shi[rb];
            bf16x8 bl = *(const bf16x8*)&slo[rb];
            int ks = sensor * 20 + t;
            size_t ab0 = ((size_t)((mt0 * 40 + ks) * 64 + lane)) * 8;
            size_t ab1 = ((size_t)((mt1 * 40 + ks) * 64 + lane)) * 8;
            bf16x8 ah0 = *(const bf16x8*)(w1ah + ab0);
            bf16x8 al0 = *(const bf16x8*)(w1al + ab0);
            bf16x8 ah1 = *(const bf16x8*)(w1ah + ab1);
            bf16x8 al1 = *(const bf16x8*)(w1al + ab1);
            zacc0 = __builtin_amdgcn_mfma_f32_16x16x32_bf16(ah0, bh, zacc0, 0, 0, 0);
            zacc0 = __builtin_amdgcn_mfma_f32_16x16x32_bf16(ah0, bl, zacc0, 0, 0, 0);
            zacc0 = __builtin_amdgcn_mfma_f32_16x16x32_bf16(al0, bh, zacc0, 0, 0, 0);
            zacc1 = __builtin_amdgcn_mfma_f32_16x16x32_bf16(ah1, bh, zacc1, 0, 0, 0);
            zacc1 = __builtin_amdgcn_mfma_f32_16x16x32_bf16(ah1, bl, zacc1, 0, 0, 0);
            zacc1 = __builtin_amdgcn_mfma_f32_16x16x32_bf16(al1, bh, zacc1, 0, 0, 0);
        }
        float* zp = Zpart + ((size_t)(sensor * NGRP + blockIdx.x)) * 2048;
#pragma unroll
        for (int r = 0; r < 4; ++r) {
            zp[mt0 * 256 + (quad * 4 + r) * 16 + e] = zacc0[r];
            zp[mt1 * 256 + (quad * 4 + r) * 16 + e] = zacc1[r];
        }
    }
#undef LOAD_FRAG
#undef LOAD_BIAS
#undef ACT_STORE
}

// ---------------------------------------------------------------------------
// fc1_w [128][1280] -> MFMA A-frag hi/lo arrays: [mt 0..7][ks 0..39][lane][8]
__global__ void w1_prep(const float* __restrict__ w1,
                        __bf16* __restrict__ w1ah, __bf16* __restrict__ w1al) {
    int t = blockIdx.x * blockDim.x + threadIdx.x;     // 8*40*64 = 20480
    if (t >= 20480) return;
    int lane = t & 63;
    int ks   = (t >> 6) % 40;
    int mt   = t / (64 * 40);
    int row  = mt * 16 + (lane & 15);
    int col0 = ks * 32 + (lane >> 4) * 8;
    const float* src = w1 + row * 1280 + col0;
#pragma unroll
    for (int j = 0; j < 8; ++j) {
        __bf16 h_, l_;
        split_trunc(src[j], h_, l_);
        w1ah[t * 8 + j] = h_;
        w1al[t * 8 + j] = l_;
    }
}

// ---------------------------------------------------------------------------
// Finisher: sum the two sensor partials, + fc1 bias, ReLU, fc2, + fc2 bias.
// Memory-bound: reads 16 MB, writes 0.3 MB.
__global__ __launch_bounds__(256, 8)
void fc_finish(const float* __restrict__ Zpart, const float* __restrict__ fc1_b,
               const float* __restrict__ fc2_w, const float* __restrict__ fc2_b,
               float* __restrict__ out) {
    const int tid = threadIdx.x;
    const int e   = tid & 15;         // batch col within group
    const int rt  = tid >> 4;         // 0..15, handles rows rt*8..rt*8+7
    const int g   = blockIdx.x;
    __shared__ float sp[16][16][5];

    const float* z0 = Zpart + (size_t)g * 2048;
    const float* z1 = Zpart + (size_t)(NGRP + g) * 2048;
    float p[5] = {0.f, 0.f, 0.f, 0.f, 0.f};
#pragma unroll
    for (int rr = 0; rr < 8; ++rr) {
        int row = rt * 8 + rr;
        int zi  = (row >> 4) * 256 + (row & 15) * 16 + e;
        float v = fmaxf(z0[zi] + z1[zi] + fc1_b[row], 0.f);
#pragma unroll
        for (int n = 0; n < 5; ++n) p[n] = fmaf(v, fc2_w[n * 128 + row], p[n]);
    }
#pragma unroll
    for (int n = 0; n < 5; ++n) sp[rt][e][n] = p[n];
    __syncthreads();
    if (tid < 80) {
        int col = tid / 5, n = tid - col * 5;
        float s = fc2_b[n];
#pragma unroll
        for (int k = 0; k < 16; ++k) s += sp[k][col][n];
        out[(size_t)(g * 16 + col) * 5 + n] = s;
    }
}

// ---------------------------------------------------------------------------
extern "C" void kernel_launch(void* const* d_in, const int* in_sizes, int n_in,
                              void* d_out, int out_size, void* d_ws, size_t ws_size,
                              hipStream_t stream) {
    const float* accel  = (const float*)d_in[0];
    const float* gyro   = (const float*)d_in[1];
    const float* aWih0  = (const float*)d_in[2];
    const float* aWihR  = (const float*)d_in[3];
    const float* aWhh   = (const float*)d_in[4];
    const float* aBih   = (const float*)d_in[5];
    const float* aBhh   = (const float*)d_in[6];
    const float* gWih0  = (const float*)d_in[7];
    const float* gWihR  = (const float*)d_in[8];
    const float* gWhh   = (const float*)d_in[9];
    const float* gBih   = (const float*)d_in[10];
    const float* gBhh   = (const float*)d_in[11];
    const float* fc1_w  = (const float*)d_in[12];
    const float* fc1_b  = (const float*)d_in[13];
    const float* fc2_w  = (const float*)d_in[14];
    const float* fc2_b  = (const float*)d_in[15];
    float* out = (float*)d_out;

    __bf16* W1ah = (__bf16*)d_ws;                     // 163,840 bf16
    __bf16* W1al = W1ah + 163840;                     // 163,840 bf16
    float*  Zpart = (float*)(W1al + 163840);          // 2*NGRP*2048 fp32 = 16 MB

    hipLaunchKernelGGL(w1_prep, dim3(80), dim3(256), 0, stream, fc1_w, W1ah, W1al);

    hipLaunchKernelGGL(lstm5_mfma, dim3(NGRP, 2), dim3(256), 0, stream,
                       accel, gyro, aWih0, aWihR, aWhh, aBih, aBhh,
                       gWih0, gWihR, gWhh, gBih, gBhh, W1ah, W1al, Zpart);

    hipLaunchKernelGGL(fc_finish, dim3(NGRP), dim3(256), 0, stream,
                       Zpart, fc1_b, fc2_w, fc2_b, out);
}